// Round 14
// baseline (201.477 us; speedup 1.0000x reference)
//
#include <hip/hip_runtime.h>

// Species-routed expert Linear as a bucketed grouped GEMM.
//   out[a] = rho[a] @ W[sym[a]] + b[sym[a]]   (NTA=65536, K=N=512, 4 species)
// R14: full queue-decoupling. vmcnt retires IN ORDER per wave, so any wave
//      that mixes {gather | B-loads | stores} serializes them at its next
//      wait. Split: 8 PRODUCER waves own the scattered rho gather (tile t+1
//      -> Abuf[p^1]); 8 CONSUMER waves own B-loads+MFMA+stores, and preload
//      tile t+1's kt0 B-frags BEFORE the tile-t store burst so the next
//      B-wait (in-order) never drains the stores. 1 block/CU (1024 thr),
//      2x64KB A dbuf, ONE lgkmcnt-only barrier per tile, persistent chains.

#define NTA   65536
#define DIM_O 512
#define NMAXD 512
#define NSPE  4

typedef __attribute__((ext_vector_type(4))) float  f32x4;
typedef __attribute__((ext_vector_type(8))) short  bf16x8;
typedef __attribute__((ext_vector_type(4))) short  bf16x4;

__device__ __forceinline__ short f2bf(float f) {
    unsigned u = __builtin_bit_cast(unsigned, f);
    u += 0x7FFFu + ((u >> 16) & 1u);
    return (short)(u >> 16);
}

// LDS-visibility barrier that does NOT drain vmcnt
__device__ __forceinline__ void bar_lds() {
    asm volatile("s_waitcnt lgkmcnt(0)" ::: "memory");
    __builtin_amdgcn_s_barrier();
    __builtin_amdgcn_sched_barrier(0);
}

__global__ void build_lists_kernel(const int* __restrict__ sym,
                                   int* __restrict__ counts,
                                   int* __restrict__ lists) {
    int i = blockIdx.x * 256 + threadIdx.x;
    int s = sym[i];
    int lane = threadIdx.x & 63;
    #pragma unroll
    for (int spe = 0; spe < NSPE; ++spe) {
        unsigned long long m = __ballot(s == spe);
        if (m == 0ull) continue;
        int leader = __ffsll(m) - 1;
        int base = 0;
        if (lane == leader) base = atomicAdd(&counts[spe], __popcll(m));
        base = __shfl(base, leader);
        if (s == spe) {
            int pos = __popcll(m & ((1ull << lane) - 1ull));
            lists[spe * NTA + base + pos] = i;
        }
    }
}

// Pack W[s][k][n] (fp32) -> bf16 MFMA-B fragment layout; also zeroes counts
// (launched BEFORE build_lists on the same stream).
__global__ void pack_w_kernel(const float* __restrict__ W, short* __restrict__ Wp,
                              int* __restrict__ counts) {
    if (blockIdx.x == 0 && threadIdx.x < NSPE) counts[threadIdx.x] = 0;
    int idx = blockIdx.x * 256 + threadIdx.x;
    int j  = idx & 7;
    int l  = (idx >> 3) & 63;
    int nb = (idx >> 9) & 31;
    int kb = (idx >> 14) & 15;
    int s  = idx >> 18;
    int k = kb * 32 + (l >> 4) * 8 + j;
    int n = nb * 16 + (l & 15);
    Wp[idx] = f2bf(W[((size_t)s * DIM_O + k) * NMAXD + n]);
}

// LDS A layout per buffer (full K): 16B slot = c*64 + (row ^ ((c&3)<<1)),
// c = k-chunk of 8 floats (0..63). Proven 0-conflict both sides (R6/R7).
__global__ __launch_bounds__(1024, 4)
void gemm_kernel(const float* __restrict__ rho,
                 const short* __restrict__ Wp,
                 const float* __restrict__ bias,
                 const int*  __restrict__ counts,
                 const int*  __restrict__ lists,
                 float* __restrict__ out)
{
    const int b    = blockIdx.x;          // 0..255, persistent chain id
    const int tid  = threadIdx.x;
    const int lane = tid & 63;
    const int w    = tid >> 6;            // 0..7 consumers, 8..15 producers

    const int c0x = counts[0], c1x = counts[1], c2x = counts[2], c3x = counts[3];
    const int P1 = (c0x + 63) >> 6;
    const int P2 = P1 + ((c1x + 63) >> 6);
    const int P3 = P2 + ((c2x + 63) >> 6);
    const int ntot = P3 + ((c3x + 63) >> 6);
    if (b >= ntot) return;

    __shared__ int aidx[2][64];
    __shared__ __align__(16) short Abuf[2][64 * 64 * 8];   // 2 x 64 KB

    #define TILE_INFO(ti, s_, mb_, cnt_)                                   \
        {   s_ = ((ti) >= P1) + ((ti) >= P2) + ((ti) >= P3);               \
            mb_ = (ti) - (s_ == 0 ? 0 : s_ == 1 ? P1 : s_ == 2 ? P2 : P3); \
            cnt_ = (s_ == 0 ? c0x : s_ == 1 ? c1x : s_ == 2 ? c2x : c3x); }

    // ---------------- producer geometry (waves 8..15) ----------------
    const int pt    = tid - 512;
    const int srow  = pt >> 3;            // 0..63
    const int scol8 = pt & 7;
    const int cc0   = scol8 >> 1;
    const int roww  = srow ^ ((cc0 & 3) << 1);
    const int dof   = (scol8 & 1) * 4;

    #define GATHER(ti_, dstp_)                                              \
        {   int s2, mb2, cnt2; TILE_INFO(ti_, s2, mb2, cnt2);               \
            if (w == 8)                                                     \
                aidx[dstp_][lane] =                                         \
                    lists[s2 * NTA + min(mb2 * 64 + lane, cnt2 - 1)];       \
            const int gi = lists[s2 * NTA + min(mb2 * 64 + srow, cnt2 - 1)];\
            const float* g = rho + (size_t)gi * DIM_O + scol8 * 4;          \
            f32x4 v[16];                                                    \
            _Pragma("unroll")                                               \
            for (int r = 0; r < 16; ++r) v[r] = *(const f32x4*)(g + r * 32);\
            short* dstb = Abuf[dstp_];                                      \
            _Pragma("unroll")                                               \
            for (int r = 0; r < 16; ++r) {                                  \
                bf16x4 a;                                                   \
                _Pragma("unroll")                                           \
                for (int q = 0; q < 4; ++q) a[q] = f2bf(v[r][q]);           \
                *(bf16x4*)&dstb[((r * 4 + cc0) * 64 + roww) * 8 + dof] = a; \
            }                                                               \
        }

    // ---------------- consumer geometry (waves 0..7) ----------------
    const int lrow = lane & 15;
    const int lgr  = lane >> 4;

    bf16x8 bfr[2][4];                     // current-kt B frags (8 x 16B)
    #define LOAD_BFR(wb_, kt_)                                              \
        _Pragma("unroll")                                                   \
        for (int ks = 0; ks < 2; ++ks)                                      \
            _Pragma("unroll")                                               \
            for (int nf = 0; nf < 4; ++nf)                                  \
                bfr[ks][nf] = *(const bf16x8*)                              \
                    ((wb_) + (size_t)(((kt_) * 2 + ks) * 32 + nf) * 512);

    // ---------------- prologue ----------------
    if (w >= 8) {
        GATHER(b, 0);                     // tile b -> Abuf[0], aidx[0]
    } else {
        int s0, mb0, cnt0; TILE_INFO(b, s0, mb0, cnt0);
        const short* wb0 = Wp + ((size_t)s0 * 512 + w * 4) * 512 + lane * 8;
        LOAD_BFR(wb0, 0);                 // kt0 B frags in flight
    }
    bar_lds();                            // Abuf[0]/aidx[0] visible

    int p = 0;
    for (int ti = b; ti < ntot; ti += 256, p ^= 1) {
        if (w < 8) {
            // ------------- consumer -------------
            int s, mb, cnt; TILE_INFO(ti, s, mb, cnt);
            const int rows_here = min(64, cnt - mb * 64);
            const short* Ab = Abuf[p];
            const short* wbase = Wp + ((size_t)s * 512 + w * 4) * 512 + lane * 8;
            const int tn = ti + 256;

            f32x4 acc[4][4];
            #pragma unroll
            for (int m = 0; m < 4; ++m)
                #pragma unroll
                for (int n = 0; n < 4; ++n) acc[m][n] = (f32x4)0.0f;

            #pragma unroll
            for (int kt = 0; kt < 8; ++kt) {
                // MFMA on the preloaded bfr (A from LDS)
                bf16x8 cur[2][4];
                #pragma unroll
                for (int ks = 0; ks < 2; ++ks)
                    #pragma unroll
                    for (int nf = 0; nf < 4; ++nf) cur[ks][nf] = bfr[ks][nf];
                // refill bfr for kt+1 (or next tile's kt0) BEFORE the stores
                if (kt < 7) {
                    LOAD_BFR(wbase, kt + 1);
                } else if (tn < ntot) {
                    int s2, mb2, cnt2; TILE_INFO(tn, s2, mb2, cnt2);
                    const short* wb2 = Wp + ((size_t)s2 * 512 + w * 4) * 512 + lane * 8;
                    LOAD_BFR(wb2, 0);
                }
                #pragma unroll
                for (int ks = 0; ks < 2; ++ks) {
                    #pragma unroll
                    for (int mf = 0; mf < 4; ++mf) {
                        const int c = kt * 8 + ks * 4 + lgr;
                        const int r = (mf * 16 + lrow) ^ ((lgr & 3) << 1);
                        const bf16x8 afrag = *(const bf16x8*)&Ab[(c * 64 + r) * 8];
                        #pragma unroll
                        for (int nf = 0; nf < 4; ++nf)
                            acc[mf][nf] = __builtin_amdgcn_mfma_f32_16x16x32_bf16(
                                afrag, cur[ks][nf], acc[mf][nf], 0, 0, 0);
                    }
                }
            }

            // stores: issued AFTER next tile's kt0 B-loads -> the next B-wait
            // (in-order vmcnt) completes without draining these.
            float bv[4];
            #pragma unroll
            for (int nf = 0; nf < 4; ++nf)
                bv[nf] = bias[s * NMAXD + w * 64 + nf * 16 + lrow];
            #pragma unroll
            for (int mf = 0; mf < 4; ++mf) {
                #pragma unroll
                for (int q = 0; q < 4; ++q) {
                    const int r = mf * 16 + lgr * 4 + q;
                    if (r < rows_here) {
                        float* orow = out + (size_t)aidx[p][r] * NMAXD + w * 64 + lrow;
                        #pragma unroll
                        for (int nf = 0; nf < 4; ++nf)
                            orow[nf * 16] = acc[mf][nf][q] + bv[nf];
                    }
                }
            }
        } else {
            // ------------- producer: gather tile ti+256 -> Abuf[p^1] -------------
            const int tn = ti + 256;
            if (tn < ntot) GATHER(tn, p ^ 1);
        }
        // one barrier per tile: consumers done READING Abuf[p], producers done
        // WRITING Abuf[p^1] -> roles swap buffers next iteration.
        bar_lds();
    }
    #undef GATHER
    #undef LOAD_BFR
    #undef TILE_INFO
}

extern "C" void kernel_launch(void* const* d_in, const int* in_sizes, int n_in,
                              void* d_out, int out_size, void* d_ws, size_t ws_size,
                              hipStream_t stream) {
    const float* rho = (const float*)d_in[0];
    const float* W   = (const float*)d_in[1];
    const float* b   = (const float*)d_in[2];
    const int*   sym = (const int*)d_in[3];
    float* out = (float*)d_out;

    int*   counts = (int*)d_ws;
    int*   lists  = (int*)((char*)d_ws + 1024);
    short* Wp     = (short*)((char*)d_ws + 1024 + (size_t)NSPE * NTA * 4);

    pack_w_kernel<<<(NSPE * DIM_O * NMAXD) / 256, 256, 0, stream>>>(W, Wp, counts);
    build_lists_kernel<<<NTA / 256, 256, 0, stream>>>(sym, counts, lists);
    gemm_kernel<<<256, 1024, 0, stream>>>(rho, Wp, b, counts, lists, out);
}